// Round 4
// baseline (333.002 us; speedup 1.0000x reference)
//
#include <hip/hip_runtime.h>
#include <hip/hip_fp16.h>

// CorrVolume1DBlock: cv[n,i,h,w] = (1/C) * sum_c x1[n,c,h,w] * x2[n,c,h,w-i],
// zero where w-i < 0.  B=8, C=128, H=128, W=256, i in [0,64], fp32 in/out.
//
// R8: duty-cycle attack. R4/R6/R7 all ran 133 us = 200 MB HBM at a pinned
// 1.5 TB/s -- memory is only in flight ~25% of the time (stage->barrier->
// compute serialization). Changes:
//  - x1 never touches LDS: loaded global->reg inside the compute loop
//    (all 4 waves hit the same lines -> L1/L2; no extra HBM).
//  - x2 only is staged (f16 channel-pair packed), double-buffered; prefetch
//    loads are pinned ABOVE compute by asm volatile("" ::: "memory") -- a
//    load cannot sink past a potential memory writer, so the R6 failure
//    (compiler sank issue() to commit()) is structurally illegal now.
//    vmcnt drain happens at first use (commit), after ~8K cycles of compute.
//  - 256-thread blocks, one per (n,h); wave qi owns i in [16qi,16qi+16),
//    qi==3 also i=64 (taps land inside the same aligned 5xb128 window).
//  - __launch_bounds__(256,3): 170-reg cap, 3 blocks/CU, 12 waves/CU.
//    acc[16][4]=64 f32 (compiler may use AGPRs - fine) + 4xfloat4 prefetch.
//  - LDS: 2 bufs x 8 c-pair rows x 320 half2 cols = 20 KB. All b128 ops at
//    16 B lane stride (conflict-free); cols [0,64) zero margin for w<i.
//  - Precision: f16 inputs, f32 accumulate -> absmax ~2e-3 vs 9.96e-3.

constexpr int B   = 8;
constexpr int C   = 128;
constexpr int H   = 128;
constexpr int W   = 256;
constexpr int NI  = 65;
constexpr int HW  = H * W;
constexpr int CHW = C * HW;
constexpr int KC2 = 8;             // c-PAIRS per chunk (16 channels)
constexpr int X2W = 320;           // x2 cols: j in [0,320) <-> w' = j-64
constexpr int NCHUNK = C / (2 * KC2);  // 8

typedef _Float16 half2v __attribute__((ext_vector_type(2)));

__device__ inline unsigned int pack2(float a, float b) {
    __half2 h = __floats2half2_rn(a, b);     // a -> low, b -> high
    return __builtin_bit_cast(unsigned int, h);
}

__device__ inline float fdot2f(unsigned int a, unsigned int b, float c) {
#if __has_builtin(__builtin_amdgcn_fdot2)
    return __builtin_amdgcn_fdot2(__builtin_bit_cast(half2v, a),
                                  __builtin_bit_cast(half2v, b), c, false);
#else
    __half2 ha = __builtin_bit_cast(__half2, a);
    __half2 hb = __builtin_bit_cast(__half2, b);
    float2 fa = __half22float2(ha), fb = __half22float2(hb);
    return fmaf(fa.x, fb.x, fmaf(fa.y, fb.y, c));
#endif
}

__global__ __launch_bounds__(256, 3)
void corr_volume_kernel(const float* __restrict__ x1,
                        const float* __restrict__ x2,
                        float* __restrict__ out) {
    const int h   = blockIdx.x;
    const int n   = blockIdx.y;
    const int tid = threadIdx.x;
    const int l   = tid & 63;        // w = 4l .. 4l+3
    const int qi  = tid >> 6;        // i-group: i = 16*qi + il, il in [0,16)

    __shared__ unsigned int x2h[2][KC2][X2W];   // 20 KB, half2 over (2c2,2c2+1)

    float acc[16][4];
    #pragma unroll
    for (int il = 0; il < 16; ++il)
        #pragma unroll
        for (int wl = 0; wl < 4; ++wl) acc[il][wl] = 0.0f;
    float acc64[4] = {0.f, 0.f, 0.f, 0.f};     // only qi==3 uses this (i=64)

    // window: LDS col j = w - i + 64 = j0a + (16 + wl - il), idx in [1,19];
    // i=64 (qi==3) lands at idx = wl in [0,4). 5 aligned uint4 per c2.
    const int j0a = 4 * l - 16 * qi + 48;   // in [0, 300], uint4-aligned

    const float* x1g = x1 + n * CHW + h * W;
    const float* x2g = x2 + n * CHW + h * W;

    // Zero-fill left margins of both buffers once (never overwritten later).
    // 2 bufs x 8 rows x 16 uint4 = 256 uint4 = one per thread.
    {
        const int bufi = tid >> 7;        // [0,2)
        const int r    = (tid >> 4) & 7;  // [0,8)
        const int cq   = tid & 15;        // cols [0,64)
        *(uint4*)&x2h[bufi][r][4 * cq] = make_uint4(0u, 0u, 0u, 0u);
    }

    // stage: wave qi covers c-pair rows {2qi, 2qi+1}; 4 loads, 2 writes.
    float4 L[4];
    auto issue = [&](int c0) {
        #pragma unroll
        for (int rr = 0; rr < 2; ++rr) {
            const int r = 2 * qi + rr;
            const float* g = x2g + (c0 + 2 * r) * HW + 4 * l;
            L[2 * rr + 0] = *(const float4*)g;          // channel 2r
            L[2 * rr + 1] = *(const float4*)(g + HW);   // channel 2r+1
        }
    };
    auto commit = [&](int bufi) {
        #pragma unroll
        for (int rr = 0; rr < 2; ++rr) {
            const int r = 2 * qi + rr;
            uint4 p;
            p.x = pack2(L[2 * rr].x, L[2 * rr + 1].x);
            p.y = pack2(L[2 * rr].y, L[2 * rr + 1].y);
            p.z = pack2(L[2 * rr].z, L[2 * rr + 1].z);
            p.w = pack2(L[2 * rr].w, L[2 * rr + 1].w);
            *(uint4*)&x2h[bufi][r][64 + 4 * l] = p;
        }
    };

    // prologue: fill buffer 0 with chunk 0
    issue(0);
    commit(0);
    __syncthreads();

    for (int t = 0; t < NCHUNK; ++t) {
        const int cur = t & 1;
        const int c0  = t * 2 * KC2;

        // prefetch next chunk's x2 into regs; the memory clobber below makes
        // sinking these loads past it illegal (asm may write what they read).
        if (t + 1 < NCHUNK) issue((t + 1) * 2 * KC2);
        asm volatile("" ::: "memory");

        #pragma unroll 2
        for (int c2 = 0; c2 < KC2; ++c2) {
            // x1 direct from global (L1/L2-hit: same lines across the 4 waves)
            const float4 lo = *(const float4*)(x1g + (c0 + 2 * c2) * HW + 4 * l);
            const float4 hi = *(const float4*)(x1g + (c0 + 2 * c2 + 1) * HW + 4 * l);
            const unsigned int aw[4] = {pack2(lo.x, hi.x), pack2(lo.y, hi.y),
                                        pack2(lo.z, hi.z), pack2(lo.w, hi.w)};
            const uint4 b0 = *(const uint4*)&x2h[cur][c2][j0a];
            const uint4 b1 = *(const uint4*)&x2h[cur][c2][j0a + 4];
            const uint4 b2 = *(const uint4*)&x2h[cur][c2][j0a + 8];
            const uint4 b3 = *(const uint4*)&x2h[cur][c2][j0a + 12];
            const uint4 b4 = *(const uint4*)&x2h[cur][c2][j0a + 16];
            const unsigned int bw[20] = {b0.x, b0.y, b0.z, b0.w,
                                         b1.x, b1.y, b1.z, b1.w,
                                         b2.x, b2.y, b2.z, b2.w,
                                         b3.x, b3.y, b3.z, b3.w,
                                         b4.x, b4.y, b4.z, b4.w};
            #pragma unroll
            for (int il = 0; il < 16; ++il)
                #pragma unroll
                for (int wl = 0; wl < 4; ++wl)
                    acc[il][wl] = fdot2f(aw[wl], bw[16 + wl - il], acc[il][wl]);

            if (qi == 3) {   // i == 64: window idx wl
                #pragma unroll
                for (int wl = 0; wl < 4; ++wl)
                    acc64[wl] = fdot2f(aw[wl], bw[wl], acc64[wl]);
            }
        }

        if (t + 1 < NCHUNK) {
            // first use of L -> vmcnt drain lands HERE (after compute)
            commit((t + 1) & 1);
            __syncthreads();
        }
    }

    // ---- epilogue: out[n, i, h, w], lane-contiguous float4 stores ----
    const float scale = 1.0f / (float)C;
    float* outg = out + n * (NI * HW) + h * W + 4 * l;
    #pragma unroll
    for (int il = 0; il < 16; ++il) {
        const int i = 16 * qi + il;
        *(float4*)(outg + i * HW) =
            make_float4(acc[il][0] * scale, acc[il][1] * scale,
                        acc[il][2] * scale, acc[il][3] * scale);
    }
    if (qi == 3) {
        *(float4*)(outg + 64 * HW) =
            make_float4(acc64[0] * scale, acc64[1] * scale,
                        acc64[2] * scale, acc64[3] * scale);
    }
}

extern "C" void kernel_launch(void* const* d_in, const int* in_sizes, int n_in,
                              void* d_out, int out_size, void* d_ws, size_t ws_size,
                              hipStream_t stream) {
    const float* x1 = (const float*)d_in[0];
    const float* x2 = (const float*)d_in[1];
    float* out = (float*)d_out;
    dim3 grid(H, B);   // 1024 blocks, one per (n, h); 3 blocks/CU resident
    corr_volume_kernel<<<grid, 256, 0, stream>>>(x1, x2, out);
}